// Round 1
// baseline (1536.295 us; speedup 1.0000x reference)
//
#include <hip/hip_runtime.h>

// 2,000,000 rows x 128 fp32 cols. 32 lanes per row, one float4 per lane.
// Rules are mutually exclusive; ~55% of rows fire with uniform inputs, so we
// skip fetching cols 32..127 (3 of 4 cachelines) for firing rows via exec-mask
// lane predication (inactive lanes generate no memory requests on CDNA).
__global__ __launch_bounds__(256) void symrule_kernel(
    const float* __restrict__ x, float* __restrict__ out, int nrows)
{
    const int tid = blockIdx.x * blockDim.x + threadIdx.x;  // max 64e6, fits int
    const int row = tid >> 5;       // 32 lanes per row
    const int cg  = tid & 31;       // float4 index within row (cols cg*4 .. cg*4+3)
    if (row >= nrows) return;

    const float4* __restrict__ xr = (const float4*)(x   + (size_t)row * 128);
    float4*       __restrict__ yr = (float4*)      (out + (size_t)row * 128);

    float4 v = make_float4(0.f, 0.f, 0.f, 0.f);
    int rule = 0;
    if (cg == 0) {
        v = xr[0];                       // hunger, social, wealth, col3
        if      (v.x > 0.8f) rule = 1;   // c1
        else if (v.y < 0.3f) rule = 2;   // c2 = !c1 && s<0.3
        else if (v.z < 0.2f) rule = 3;   // c3 = !c1 && !c2 && w<0.2
    }
    // broadcast rule from lane 0 of each 32-lane row-group (wave64 -> 2 groups)
    rule = __shfl(rule, 0, 32);

    float4 o;
    if (rule == 0) {
        if (cg != 0) v = xr[cg];         // passthrough: load rest of row
        o = v;
    } else {
        o = make_float4(0.f, 0.f, 0.f, 0.f);
        if (cg == 0) {                   // one-hot at column rule-1
            if      (rule == 1) o.x = 1.0f;
            else if (rule == 2) o.y = 1.0f;
            else                o.z = 1.0f;
        }
    }
    yr[cg] = o;                          // full-row coalesced float4 stores
}

extern "C" void kernel_launch(void* const* d_in, const int* in_sizes, int n_in,
                              void* d_out, int out_size, void* d_ws, size_t ws_size,
                              hipStream_t stream) {
    const float* x = (const float*)d_in[0];
    float* out = (float*)d_out;
    const int nrows = in_sizes[0] / 128;         // 2,000,000
    const long long threads = (long long)nrows * 32;
    const int block = 256;
    const int grid = (int)((threads + block - 1) / block);  // 250,000 blocks
    symrule_kernel<<<grid, block, 0, stream>>>(x, out, nrows);
}